// Round 1
// baseline (883.344 us; speedup 1.0000x reference)
//
#include <hip/hip_runtime.h>
#include <hip/hip_bf16.h>

#define NB 4
#define SEQ 1024
#define DMODEL 1024
#define NH 16
#define DH 64
#define SCALE_F 0.125f
#define ZTH 1.5f

// ---------------------------------------------------------------------------
// Tiled fp32 GEMM: C[M][Ncol] = A[M][K] * Bm[Ncol][K]^T  (both K-contiguous)
// MODE 0: qkv — scatter cols to q/k/v laid out [b*NH+h][tok][DH]
// MODE 1: plain row-major out + bias
// 64x64 tile, BK=16, 256 threads, 4x4 per-thread micro-tile.
// ---------------------------------------------------------------------------
template<int MODE>
__global__ __launch_bounds__(256)
void gemm_nt_64(const float* __restrict__ A, const float* __restrict__ Bm,
                const float* __restrict__ bias,
                float* __restrict__ C0, float* __restrict__ C1, float* __restrict__ C2,
                int M, int Ncol, int K)
{
    __shared__ float As[64][20];   // [m][k], pad 20 keeps float4 alignment
    __shared__ float Bs[16][68];   // [k][n], pad 68 keeps float4 alignment
    const int tid = threadIdx.x;
    const int tx = tid & 15, ty = tid >> 4;
    const int mBase = blockIdx.y * 64, nBase = blockIdx.x * 64;
    const int lrow = tid >> 2, lq = tid & 3;

    float acc[4][4] = {{0.f}};

    for (int k0 = 0; k0 < K; k0 += 16) {
        float4 av = *(const float4*)(A  + (size_t)(mBase + lrow) * K + k0 + lq * 4);
        float4 bv = *(const float4*)(Bm + (size_t)(nBase + lrow) * K + k0 + lq * 4);
        __syncthreads();   // protect LDS from previous-iteration readers
        *(float4*)&As[lrow][lq * 4] = av;
        Bs[lq * 4 + 0][lrow] = bv.x;
        Bs[lq * 4 + 1][lrow] = bv.y;
        Bs[lq * 4 + 2][lrow] = bv.z;
        Bs[lq * 4 + 3][lrow] = bv.w;
        __syncthreads();

        #pragma unroll
        for (int kg = 0; kg < 16; kg += 4) {
            float4 a4[4];
            #pragma unroll
            for (int i = 0; i < 4; ++i)
                a4[i] = *(const float4*)&As[ty * 4 + i][kg];
            #pragma unroll
            for (int t = 0; t < 4; ++t) {
                float4 b4 = *(const float4*)&Bs[kg + t][tx * 4];
                #pragma unroll
                for (int i = 0; i < 4; ++i) {
                    float avs = (t == 0) ? a4[i].x : (t == 1) ? a4[i].y
                              : (t == 2) ? a4[i].z : a4[i].w;
                    acc[i][0] = fmaf(avs, b4.x, acc[i][0]);
                    acc[i][1] = fmaf(avs, b4.y, acc[i][1]);
                    acc[i][2] = fmaf(avs, b4.z, acc[i][2]);
                    acc[i][3] = fmaf(avs, b4.w, acc[i][3]);
                }
            }
        }
    }

    if constexpr (MODE == 0) {
        // nBase is 64-aligned -> whole tile maps to one (which, head), d = tx*4+j
        const int which = nBase >> 10;
        const int h = (nBase >> 6) & 15;
        float* dst = (which == 0) ? C0 : (which == 1) ? C1 : C2;
        #pragma unroll
        for (int i = 0; i < 4; ++i) {
            int m = mBase + ty * 4 + i;
            int b = m >> 10, tok = m & 1023;
            float4 o; o.x = acc[i][0]; o.y = acc[i][1]; o.z = acc[i][2]; o.w = acc[i][3];
            *(float4*)&dst[(((size_t)(b * NH + h)) * SEQ + tok) * DH + tx * 4] = o;
        }
    } else {
        const float4 bb = *(const float4*)&bias[nBase + tx * 4];
        #pragma unroll
        for (int i = 0; i < 4; ++i) {
            int m = mBase + ty * 4 + i;
            float4 o; o.x = acc[i][0] + bb.x; o.y = acc[i][1] + bb.y;
                      o.z = acc[i][2] + bb.z; o.w = acc[i][3] + bb.w;
            *(float4*)&C0[(size_t)m * Ncol + nBase + tx * 4] = o;
        }
    }
}

// ---------------------------------------------------------------------------
// Pass 1: per (b,h), 64-row tile. Computes diag of softmax(dots) without
// materializing dots: row sum of exp(s) + the diagonal logit.
// No max-subtraction: |dots| <= ~6 so exp cannot overflow (identical math).
// ---------------------------------------------------------------------------
__global__ __launch_bounds__(256)
void attn_pass1(const float* __restrict__ q, const float* __restrict__ kmat,
                float* __restrict__ diag)
{
    __shared__ float Qs[64][68];   // [row][d]
    __shared__ float Kt[64][68];   // [d][col]  (transposed on store)
    const int bh = blockIdx.x, rt = blockIdx.y;
    const int tid = threadIdx.x;
    const int tx = tid & 15, ty = tid >> 4;
    const float* qb = q + (((size_t)bh * SEQ) + rt * 64) * DH;

    #pragma unroll
    for (int l = 0; l < 4; ++l) {
        int fid = tid + l * 256;
        int r = fid >> 4, dq = fid & 15;
        *(float4*)&Qs[r][dq * 4] = *(const float4*)(qb + r * DH + dq * 4);
    }

    float lsum[4]  = {0.f, 0.f, 0.f, 0.f};
    float sdiag[4] = {-1e30f, -1e30f, -1e30f, -1e30f};

    for (int jt = 0; jt < 16; ++jt) {
        const float* kb = kmat + (((size_t)bh * SEQ) + jt * 64) * DH;
        __syncthreads();
        #pragma unroll
        for (int l = 0; l < 4; ++l) {
            int fid = tid + l * 256;
            int r = fid >> 4, dq = fid & 15;
            float4 kv = *(const float4*)(kb + r * DH + dq * 4);
            Kt[dq * 4 + 0][r] = kv.x;
            Kt[dq * 4 + 1][r] = kv.y;
            Kt[dq * 4 + 2][r] = kv.z;
            Kt[dq * 4 + 3][r] = kv.w;
        }
        __syncthreads();

        float s[4][4] = {{0.f}};
        #pragma unroll
        for (int dg = 0; dg < 64; dg += 4) {
            float4 a4[4];
            #pragma unroll
            for (int i = 0; i < 4; ++i)
                a4[i] = *(const float4*)&Qs[ty * 4 + i][dg];
            #pragma unroll
            for (int t = 0; t < 4; ++t) {
                float4 b4 = *(const float4*)&Kt[dg + t][tx * 4];
                #pragma unroll
                for (int i = 0; i < 4; ++i) {
                    float avs = (t == 0) ? a4[i].x : (t == 1) ? a4[i].y
                              : (t == 2) ? a4[i].z : a4[i].w;
                    s[i][0] = fmaf(avs, b4.x, s[i][0]);
                    s[i][1] = fmaf(avs, b4.y, s[i][1]);
                    s[i][2] = fmaf(avs, b4.z, s[i][2]);
                    s[i][3] = fmaf(avs, b4.w, s[i][3]);
                }
            }
        }

        #pragma unroll
        for (int i = 0; i < 4; ++i) {
            #pragma unroll
            for (int j = 0; j < 4; ++j) {
                float sv = s[i][j] * SCALE_F;
                lsum[i] += __expf(sv);
                if (jt == rt && (tx * 4 + j) == (ty * 4 + i)) sdiag[i] = sv;
            }
        }
    }

    #pragma unroll
    for (int i = 0; i < 4; ++i) {
        #pragma unroll
        for (int off = 8; off; off >>= 1) {
            lsum[i]  += __shfl_xor(lsum[i], off, 16);
            sdiag[i]  = fmaxf(sdiag[i], __shfl_xor(sdiag[i], off, 16));
        }
    }
    if (tx == 0) {
        #pragma unroll
        for (int i = 0; i < 4; ++i) {
            int tok = rt * 64 + ty * 4 + i;
            diag[(size_t)bh * SEQ + tok] = __expf(sdiag[i]) / lsum[i];
        }
    }
}

// ---------------------------------------------------------------------------
// Per-(b,h) z-score mask: mu, std(ddof=1) over diag[1024], keep = |z|<=1.5
// ---------------------------------------------------------------------------
__global__ __launch_bounds__(256)
void mask_stats(const float* __restrict__ diag, unsigned char* __restrict__ keep)
{
    __shared__ float red[256];
    const int bh = blockIdx.x, tid = threadIdx.x;
    const float* d = diag + (size_t)bh * SEQ;
    float4 v = *(const float4*)(d + tid * 4);
    red[tid] = (v.x + v.y) + (v.z + v.w);
    __syncthreads();
    for (int w = 128; w > 0; w >>= 1) {
        if (tid < w) red[tid] += red[tid + w];
        __syncthreads();
    }
    float mu = red[0] * (1.0f / 1024.0f);
    __syncthreads();
    float dx0 = v.x - mu, dx1 = v.y - mu, dx2 = v.z - mu, dx3 = v.w - mu;
    red[tid] = (dx0 * dx0 + dx1 * dx1) + (dx2 * dx2 + dx3 * dx3);
    __syncthreads();
    for (int w = 128; w > 0; w >>= 1) {
        if (tid < w) red[tid] += red[tid + w];
        __syncthreads();
    }
    float sd = sqrtf(red[0] * (1.0f / 1023.0f));
    uchar4 kv;
    kv.x = (fabsf(dx0 / sd) <= ZTH) ? 1 : 0;
    kv.y = (fabsf(dx1 / sd) <= ZTH) ? 1 : 0;
    kv.z = (fabsf(dx2 / sd) <= ZTH) ? 1 : 0;
    kv.w = (fabsf(dx3 / sd) <= ZTH) ? 1 : 0;
    *(uchar4*)&keep[(size_t)bh * SEQ + tid * 4] = kv;
}

// ---------------------------------------------------------------------------
// Pass 2: recompute dots, masked softmax (no max needed), attn @ V.
// Output att laid out [b][tok][h*DH+d] so the out-proj GEMM reads it directly.
// ---------------------------------------------------------------------------
__global__ __launch_bounds__(256)
void attn_pass2(const float* __restrict__ q, const float* __restrict__ kmat,
                const float* __restrict__ vmat, const unsigned char* __restrict__ keep,
                float* __restrict__ att)
{
    __shared__ float Qs[64][68];
    __shared__ float Kt[64][68];
    __shared__ float Vs[64][68];   // [col j][d]
    __shared__ float Ps[64][68];   // [row][col j]
    const int bh = blockIdx.x, rt = blockIdx.y;
    const int b = bh >> 4, h = bh & 15;
    const int tid = threadIdx.x;
    const int tx = tid & 15, ty = tid >> 4;
    const float* qb = q + (((size_t)bh * SEQ) + rt * 64) * DH;

    #pragma unroll
    for (int l = 0; l < 4; ++l) {
        int fid = tid + l * 256;
        int r = fid >> 4, dq = fid & 15;
        *(float4*)&Qs[r][dq * 4] = *(const float4*)(qb + r * DH + dq * 4);
    }

    int rowkeep[4];
    #pragma unroll
    for (int i = 0; i < 4; ++i)
        rowkeep[i] = keep[(size_t)bh * SEQ + rt * 64 + ty * 4 + i];

    float acc[4][4] = {{0.f}};
    float lsum[4] = {0.f, 0.f, 0.f, 0.f};

    for (int jt = 0; jt < 16; ++jt) {
        const float* kb = kmat + (((size_t)bh * SEQ) + jt * 64) * DH;
        const float* vb = vmat + (((size_t)bh * SEQ) + jt * 64) * DH;
        __syncthreads();   // previous PV readers of Kt/Vs/Ps are done
        #pragma unroll
        for (int l = 0; l < 4; ++l) {
            int fid = tid + l * 256;
            int r = fid >> 4, dq = fid & 15;
            float4 kv = *(const float4*)(kb + r * DH + dq * 4);
            Kt[dq * 4 + 0][r] = kv.x;
            Kt[dq * 4 + 1][r] = kv.y;
            Kt[dq * 4 + 2][r] = kv.z;
            Kt[dq * 4 + 3][r] = kv.w;
            *(float4*)&Vs[r][dq * 4] = *(const float4*)(vb + r * DH + dq * 4);
        }
        __syncthreads();

        float s[4][4] = {{0.f}};
        #pragma unroll
        for (int dg = 0; dg < 64; dg += 4) {
            float4 a4[4];
            #pragma unroll
            for (int i = 0; i < 4; ++i)
                a4[i] = *(const float4*)&Qs[ty * 4 + i][dg];
            #pragma unroll
            for (int t = 0; t < 4; ++t) {
                float4 b4 = *(const float4*)&Kt[dg + t][tx * 4];
                #pragma unroll
                for (int i = 0; i < 4; ++i) {
                    float avs = (t == 0) ? a4[i].x : (t == 1) ? a4[i].y
                              : (t == 2) ? a4[i].z : a4[i].w;
                    s[i][0] = fmaf(avs, b4.x, s[i][0]);
                    s[i][1] = fmaf(avs, b4.y, s[i][1]);
                    s[i][2] = fmaf(avs, b4.z, s[i][2]);
                    s[i][3] = fmaf(avs, b4.w, s[i][3]);
                }
            }
        }

        int kj[4];
        #pragma unroll
        for (int j = 0; j < 4; ++j)
            kj[j] = keep[(size_t)bh * SEQ + jt * 64 + tx * 4 + j];

        #pragma unroll
        for (int i = 0; i < 4; ++i) {
            #pragma unroll
            for (int j = 0; j < 4; ++j) {
                float p = (rowkeep[i] && kj[j]) ? __expf(s[i][j] * SCALE_F) : 0.f;
                lsum[i] += p;
                Ps[ty * 4 + i][tx * 4 + j] = p;
            }
        }
        __syncthreads();

        #pragma unroll 8
        for (int jj = 0; jj < 64; ++jj) {
            float4 vv = *(const float4*)&Vs[jj][tx * 4];
            float pr[4];
            #pragma unroll
            for (int i = 0; i < 4; ++i) pr[i] = Ps[ty * 4 + i][jj];
            #pragma unroll
            for (int i = 0; i < 4; ++i) {
                acc[i][0] = fmaf(pr[i], vv.x, acc[i][0]);
                acc[i][1] = fmaf(pr[i], vv.y, acc[i][1]);
                acc[i][2] = fmaf(pr[i], vv.z, acc[i][2]);
                acc[i][3] = fmaf(pr[i], vv.w, acc[i][3]);
            }
        }
    }

    #pragma unroll
    for (int i = 0; i < 4; ++i) {
        #pragma unroll
        for (int off = 8; off; off >>= 1)
            lsum[i] += __shfl_xor(lsum[i], off, 16);
    }

    #pragma unroll
    for (int i = 0; i < 4; ++i) {
        int tok = rt * 64 + ty * 4 + i;
        float inv = rowkeep[i] ? 1.0f / lsum[i] : 0.0f;
        float4 o;
        o.x = acc[i][0] * inv; o.y = acc[i][1] * inv;
        o.z = acc[i][2] * inv; o.w = acc[i][3] * inv;
        *(float4*)&att[((size_t)(b * SEQ + tok)) * DMODEL + h * DH + tx * 4] = o;
    }
}

// ---------------------------------------------------------------------------
extern "C" void kernel_launch(void* const* d_in, const int* in_sizes, int n_in,
                              void* d_out, int out_size, void* d_ws, size_t ws_size,
                              hipStream_t stream)
{
    const float* x     = (const float*)d_in[0];
    const float* w_qkv = (const float*)d_in[1];
    const float* w_out = (const float*)d_in[2];
    const float* b_out = (const float*)d_in[3];
    float* out = (float*)d_out;

    char* ws = (char*)d_ws;
    const size_t szHeads = (size_t)NB * NH * SEQ * DH * sizeof(float);   // 16.78 MB
    float* q    = (float*)(ws);
    float* k    = (float*)(ws + szHeads);
    float* v    = (float*)(ws + 2 * szHeads);
    float* att  = (float*)(ws + 3 * szHeads);
    float* diag = (float*)(ws + 4 * szHeads);
    unsigned char* keep = (unsigned char*)(ws + 4 * szHeads + (size_t)NB * NH * SEQ * sizeof(float));

    // 1) QKV projection, scattered into [b*NH+h][tok][DH]
    dim3 gQKV(3 * DMODEL / 64, (NB * SEQ) / 64);
    gemm_nt_64<0><<<gQKV, 256, 0, stream>>>(x, w_qkv, nullptr, q, k, v,
                                            NB * SEQ, 3 * DMODEL, DMODEL);

    // 2) softmax diagonal
    dim3 gAtt(NB * NH, SEQ / 64);
    attn_pass1<<<gAtt, 256, 0, stream>>>(q, k, diag);

    // 3) z-score mask
    mask_stats<<<NB * NH, 256, 0, stream>>>(diag, keep);

    // 4) masked softmax + PV
    attn_pass2<<<gAtt, 256, 0, stream>>>(q, k, v, keep, att);

    // 5) output projection + bias
    dim3 gPrj(DMODEL / 64, (NB * SEQ) / 64);
    gemm_nt_64<1><<<gPrj, 256, 0, stream>>>(att, w_out, b_out, out, nullptr, nullptr,
                                            NB * SEQ, DMODEL, DMODEL);
}

// Round 2
// 558.354 us; speedup vs baseline: 1.5821x; 1.5821x over previous
//
#include <hip/hip_runtime.h>
#include <hip/hip_bf16.h>

#define NB 4
#define SEQ 1024
#define DMODEL 1024
#define NH 16
#define DH 64
#define SCALE_F 0.125f
#define ZTH 1.5f

typedef __bf16 bf16x8 __attribute__((ext_vector_type(8)));
typedef float f32x4 __attribute__((ext_vector_type(4)));
typedef unsigned short u16;
typedef unsigned int u32;

// ---------------------------------------------------------------------------
// Decompose fp32 -> bf16 hi + bf16 lo (both round-to-nearest).
// a = hi + lo + r, |r| <~ 2^-17 |a|.  8 floats per thread, 16B stores.
// ---------------------------------------------------------------------------
__global__ __launch_bounds__(256)
void decompose_hilo(const float* __restrict__ in, u16* __restrict__ hi,
                    u16* __restrict__ lo, int n8)
{
    int i = blockIdx.x * 256 + threadIdx.x;
    if (i >= n8) return;
    const float4* p = (const float4*)in + (size_t)i * 2;
    float4 v0 = p[0], v1 = p[1];
    float f[8] = {v0.x, v0.y, v0.z, v0.w, v1.x, v1.y, v1.z, v1.w};
    u32 h[8], l[8];
    #pragma unroll
    for (int j = 0; j < 8; ++j) {
        u32 u = __float_as_uint(f[j]);
        u32 rh = (u + 0x7fffu + ((u >> 16) & 1u)) & 0xffff0000u;
        h[j] = rh >> 16;
        float fl = f[j] - __uint_as_float(rh);
        u32 ul = __float_as_uint(fl);
        l[j] = (ul + 0x7fffu + ((ul >> 16) & 1u)) >> 16;
    }
    uint4 ho, lw;
    ho.x = h[0] | (h[1] << 16); ho.y = h[2] | (h[3] << 16);
    ho.z = h[4] | (h[5] << 16); ho.w = h[6] | (h[7] << 16);
    lw.x = l[0] | (l[1] << 16); lw.y = l[2] | (l[3] << 16);
    lw.z = l[4] | (l[5] << 16); lw.w = l[6] | (l[7] << 16);
    ((uint4*)hi)[i] = ho;
    ((uint4*)lo)[i] = lw;
}

// ---------------------------------------------------------------------------
// Split-bf16 MFMA GEMM: C[M][N] = A[M][K] * B[N][K]^T  (both K-contiguous),
// A,B given as bf16 hi/lo pairs; acc = ah*bh + ah*bl + al*bh (fp32 MFMA acc).
// 128x128 tile, BK=32, 256 threads = 4 waves, each wave a 64x64 quadrant of
// 4x4 mfma_f32_16x16x32_bf16 fragments.
// LDS: [tensor][kblk][row ^ kblk][8 u16] -> conflict-free ds_read_b128.
// MODE 0: qkv (N=3072), scatter cols to q/k/v [b*NH+h][tok][DH]
// MODE 1: out-proj (N=1024), row-major + bias
// ---------------------------------------------------------------------------
template<int MODE>
__global__ __launch_bounds__(256, 2)
void gemm_split(const u16* __restrict__ Ah, const u16* __restrict__ Al,
                const u16* __restrict__ Bh, const u16* __restrict__ Bl,
                const float* __restrict__ bias,
                float* __restrict__ C0, float* __restrict__ C1, float* __restrict__ C2)
{
    constexpr int M = NB * SEQ;                       // 4096
    constexpr int NCOL = (MODE == 0) ? 3 * DMODEL : DMODEL;
    constexpr int K = DMODEL;                         // 1024
    constexpr int NTN = NCOL / 128;
    constexpr int NWG = (M / 128) * NTN;              // 768 or 256, %8==0

    __shared__ u16 lds[4][4][128][8];                 // 32 KiB

    const int tid = threadIdx.x;
    const int bid = blockIdx.x;
    const int swz = (bid & 7) * (NWG >> 3) + (bid >> 3);   // bijective XCD swizzle
    const int mBase = (swz / NTN) * 128;
    const int nBase = (swz % NTN) * 128;

    const int wave = tid >> 6, lane = tid & 63;
    const int wr = wave >> 1, wc = wave & 1;
    const int rsel = lane & 15, ks = lane >> 4;

    // ---- staging assignment: per tensor, ids {tid, tid+256}: row=id>>2, c=id&3
    const int r0 = tid >> 2, c0 = tid & 3;
    const size_t aoff0 = (size_t)(mBase + r0) * K + c0 * 8;
    const size_t aoff1 = (size_t)(mBase + 64 + r0) * K + c0 * 8;
    const size_t boff0 = (size_t)(nBase + r0) * K + c0 * 8;
    const size_t boff1 = (size_t)(nBase + 64 + r0) * K + c0 * 8;
    const int wrow0 = r0 ^ c0, wrow1 = (r0 ^ c0) + 64;

    uint4* wAh0 = (uint4*)&lds[0][c0][wrow0][0];
    uint4* wAh1 = (uint4*)&lds[0][c0][wrow1][0];
    uint4* wAl0 = (uint4*)&lds[1][c0][wrow0][0];
    uint4* wAl1 = (uint4*)&lds[1][c0][wrow1][0];
    uint4* wBh0 = (uint4*)&lds[2][c0][wrow0][0];
    uint4* wBh1 = (uint4*)&lds[2][c0][wrow1][0];
    uint4* wBl0 = (uint4*)&lds[3][c0][wrow0][0];
    uint4* wBl1 = (uint4*)&lds[3][c0][wrow1][0];

    // ---- fragment read pointers (conflict-free: lanes 0-15 hit consecutive 16B)
    const bf16x8 *rAh[4], *rAl[4], *rBh[4], *rBl[4];
    #pragma unroll
    for (int m = 0; m < 4; ++m) {
        int ar = (wr * 64 + m * 16 + rsel) ^ ks;
        rAh[m] = (const bf16x8*)&lds[0][ks][ar][0];
        rAl[m] = (const bf16x8*)&lds[1][ks][ar][0];
    }
    #pragma unroll
    for (int n = 0; n < 4; ++n) {
        int bc = (wc * 64 + n * 16 + rsel) ^ ks;
        rBh[n] = (const bf16x8*)&lds[2][ks][bc][0];
        rBl[n] = (const bf16x8*)&lds[3][ks][bc][0];
    }

    f32x4 acc[4][4];
    #pragma unroll
    for (int m = 0; m < 4; ++m)
        #pragma unroll
        for (int n = 0; n < 4; ++n)
            acc[m][n] = (f32x4)0.0f;

    uint4 sAh0, sAh1, sAl0, sAl1, sBh0, sBh1, sBl0, sBl1;
    #define LOADS(k0)                                              \
        sAh0 = *(const uint4*)(Ah + aoff0 + (k0));                 \
        sAh1 = *(const uint4*)(Ah + aoff1 + (k0));                 \
        sAl0 = *(const uint4*)(Al + aoff0 + (k0));                 \
        sAl1 = *(const uint4*)(Al + aoff1 + (k0));                 \
        sBh0 = *(const uint4*)(Bh + boff0 + (k0));                 \
        sBh1 = *(const uint4*)(Bh + boff1 + (k0));                 \
        sBl0 = *(const uint4*)(Bl + boff0 + (k0));                 \
        sBl1 = *(const uint4*)(Bl + boff1 + (k0));

    LOADS(0)

    for (int it = 0; it < K / 32; ++it) {
        __syncthreads();              // previous iteration's ds_reads done
        *wAh0 = sAh0; *wAh1 = sAh1; *wAl0 = sAl0; *wAl1 = sAl1;
        *wBh0 = sBh0; *wBh1 = sBh1; *wBl0 = sBl0; *wBl1 = sBl1;
        __syncthreads();              // writes visible
        if (it < K / 32 - 1) {        // prefetch next tile under the MFMA cluster
            int k0 = (it + 1) * 32;
            LOADS(k0)
        }
        bf16x8 ah[4], al[4], bh[4], bl[4];
        #pragma unroll
        for (int m = 0; m < 4; ++m) { ah[m] = *rAh[m]; al[m] = *rAl[m]; }
        #pragma unroll
        for (int n = 0; n < 4; ++n) { bh[n] = *rBh[n]; bl[n] = *rBl[n]; }
        #pragma unroll
        for (int m = 0; m < 4; ++m)
            #pragma unroll
            for (int n = 0; n < 4; ++n) {
                acc[m][n] = __builtin_amdgcn_mfma_f32_16x16x32_bf16(ah[m], bh[n], acc[m][n], 0, 0, 0);
                acc[m][n] = __builtin_amdgcn_mfma_f32_16x16x32_bf16(ah[m], bl[n], acc[m][n], 0, 0, 0);
                acc[m][n] = __builtin_amdgcn_mfma_f32_16x16x32_bf16(al[m], bh[n], acc[m][n], 0, 0, 0);
            }
    }
    #undef LOADS

    // ---- epilogue: C/D mapping col = lane&15, row = (lane>>4)*4 + reg
    const int rowq = lane >> 4;
    #pragma unroll
    for (int m = 0; m < 4; ++m) {
        #pragma unroll
        for (int n = 0; n < 4; ++n) {
            int grow0 = mBase + wr * 64 + m * 16 + rowq * 4;
            int gcol  = nBase + wc * 64 + n * 16 + rsel;
            if constexpr (MODE == 0) {
                int which = gcol >> 10, h = (gcol >> 6) & 15, d = gcol & 63;
                float* dst = (which == 0) ? C0 : (which == 1) ? C1 : C2;
                #pragma unroll
                for (int r = 0; r < 4; ++r) {
                    int grow = grow0 + r;
                    int b = grow >> 10, tok = grow & 1023;
                    dst[(((size_t)(b * NH + h)) * SEQ + tok) * DH + d] = acc[m][n][r];
                }
            } else {
                float bb = bias[gcol];
                #pragma unroll
                for (int r = 0; r < 4; ++r)
                    C0[(size_t)(grow0 + r) * NCOL + gcol] = acc[m][n][r] + bb;
            }
        }
    }
}

// ---------------------------------------------------------------------------
// Pass 1: diag of softmax(dots) per (b,h) — fp32, unchanged (protects mask).
// ---------------------------------------------------------------------------
__global__ __launch_bounds__(256)
void attn_pass1(const float* __restrict__ q, const float* __restrict__ kmat,
                float* __restrict__ diag)
{
    __shared__ float Qs[64][68];
    __shared__ float Kt[64][68];
    const int bh = blockIdx.x, rt = blockIdx.y;
    const int tid = threadIdx.x;
    const int tx = tid & 15, ty = tid >> 4;
    const float* qb = q + (((size_t)bh * SEQ) + rt * 64) * DH;

    #pragma unroll
    for (int l = 0; l < 4; ++l) {
        int fid = tid + l * 256;
        int r = fid >> 4, dq = fid & 15;
        *(float4*)&Qs[r][dq * 4] = *(const float4*)(qb + r * DH + dq * 4);
    }

    float lsum[4]  = {0.f, 0.f, 0.f, 0.f};
    float sdiag[4] = {-1e30f, -1e30f, -1e30f, -1e30f};

    for (int jt = 0; jt < 16; ++jt) {
        const float* kb = kmat + (((size_t)bh * SEQ) + jt * 64) * DH;
        __syncthreads();
        #pragma unroll
        for (int l = 0; l < 4; ++l) {
            int fid = tid + l * 256;
            int r = fid >> 4, dq = fid & 15;
            float4 kv = *(const float4*)(kb + r * DH + dq * 4);
            Kt[dq * 4 + 0][r] = kv.x;
            Kt[dq * 4 + 1][r] = kv.y;
            Kt[dq * 4 + 2][r] = kv.z;
            Kt[dq * 4 + 3][r] = kv.w;
        }
        __syncthreads();

        float s[4][4] = {{0.f}};
        #pragma unroll
        for (int dg = 0; dg < 64; dg += 4) {
            float4 a4[4];
            #pragma unroll
            for (int i = 0; i < 4; ++i)
                a4[i] = *(const float4*)&Qs[ty * 4 + i][dg];
            #pragma unroll
            for (int t = 0; t < 4; ++t) {
                float4 b4 = *(const float4*)&Kt[dg + t][tx * 4];
                #pragma unroll
                for (int i = 0; i < 4; ++i) {
                    float avs = (t == 0) ? a4[i].x : (t == 1) ? a4[i].y
                              : (t == 2) ? a4[i].z : a4[i].w;
                    s[i][0] = fmaf(avs, b4.x, s[i][0]);
                    s[i][1] = fmaf(avs, b4.y, s[i][1]);
                    s[i][2] = fmaf(avs, b4.z, s[i][2]);
                    s[i][3] = fmaf(avs, b4.w, s[i][3]);
                }
            }
        }

        #pragma unroll
        for (int i = 0; i < 4; ++i) {
            #pragma unroll
            for (int j = 0; j < 4; ++j) {
                float sv = s[i][j] * SCALE_F;
                lsum[i] += __expf(sv);
                if (jt == rt && (tx * 4 + j) == (ty * 4 + i)) sdiag[i] = sv;
            }
        }
    }

    #pragma unroll
    for (int i = 0; i < 4; ++i) {
        #pragma unroll
        for (int off = 8; off; off >>= 1) {
            lsum[i]  += __shfl_xor(lsum[i], off, 16);
            sdiag[i]  = fmaxf(sdiag[i], __shfl_xor(sdiag[i], off, 16));
        }
    }
    if (tx == 0) {
        #pragma unroll
        for (int i = 0; i < 4; ++i) {
            int tok = rt * 64 + ty * 4 + i;
            diag[(size_t)bh * SEQ + tok] = __expf(sdiag[i]) / lsum[i];
        }
    }
}

// ---------------------------------------------------------------------------
__global__ __launch_bounds__(256)
void mask_stats(const float* __restrict__ diag, unsigned char* __restrict__ keep)
{
    __shared__ float red[256];
    const int bh = blockIdx.x, tid = threadIdx.x;
    const float* d = diag + (size_t)bh * SEQ;
    float4 v = *(const float4*)(d + tid * 4);
    red[tid] = (v.x + v.y) + (v.z + v.w);
    __syncthreads();
    for (int w = 128; w > 0; w >>= 1) {
        if (tid < w) red[tid] += red[tid + w];
        __syncthreads();
    }
    float mu = red[0] * (1.0f / 1024.0f);
    __syncthreads();
    float dx0 = v.x - mu, dx1 = v.y - mu, dx2 = v.z - mu, dx3 = v.w - mu;
    red[tid] = (dx0 * dx0 + dx1 * dx1) + (dx2 * dx2 + dx3 * dx3);
    __syncthreads();
    for (int w = 128; w > 0; w >>= 1) {
        if (tid < w) red[tid] += red[tid + w];
        __syncthreads();
    }
    float sd = sqrtf(red[0] * (1.0f / 1023.0f));
    uchar4 kv;
    kv.x = (fabsf(dx0 / sd) <= ZTH) ? 1 : 0;
    kv.y = (fabsf(dx1 / sd) <= ZTH) ? 1 : 0;
    kv.z = (fabsf(dx2 / sd) <= ZTH) ? 1 : 0;
    kv.w = (fabsf(dx3 / sd) <= ZTH) ? 1 : 0;
    *(uchar4*)&keep[(size_t)bh * SEQ + tid * 4] = kv;
}

// ---------------------------------------------------------------------------
__global__ __launch_bounds__(256)
void attn_pass2(const float* __restrict__ q, const float* __restrict__ kmat,
                const float* __restrict__ vmat, const unsigned char* __restrict__ keep,
                float* __restrict__ att)
{
    __shared__ float Qs[64][68];
    __shared__ float Kt[64][68];
    __shared__ float Vs[64][68];
    __shared__ float Ps[64][68];
    const int bh = blockIdx.x, rt = blockIdx.y;
    const int b = bh >> 4, h = bh & 15;
    const int tid = threadIdx.x;
    const int tx = tid & 15, ty = tid >> 4;
    const float* qb = q + (((size_t)bh * SEQ) + rt * 64) * DH;

    #pragma unroll
    for (int l = 0; l < 4; ++l) {
        int fid = tid + l * 256;
        int r = fid >> 4, dq = fid & 15;
        *(float4*)&Qs[r][dq * 4] = *(const float4*)(qb + r * DH + dq * 4);
    }

    int rowkeep[4];
    #pragma unroll
    for (int i = 0; i < 4; ++i)
        rowkeep[i] = keep[(size_t)bh * SEQ + rt * 64 + ty * 4 + i];

    float acc[4][4] = {{0.f}};
    float lsum[4] = {0.f, 0.f, 0.f, 0.f};

    for (int jt = 0; jt < 16; ++jt) {
        const float* kb = kmat + (((size_t)bh * SEQ) + jt * 64) * DH;
        const float* vb = vmat + (((size_t)bh * SEQ) + jt * 64) * DH;
        __syncthreads();
        #pragma unroll
        for (int l = 0; l < 4; ++l) {
            int fid = tid + l * 256;
            int r = fid >> 4, dq = fid & 15;
            float4 kv = *(const float4*)(kb + r * DH + dq * 4);
            Kt[dq * 4 + 0][r] = kv.x;
            Kt[dq * 4 + 1][r] = kv.y;
            Kt[dq * 4 + 2][r] = kv.z;
            Kt[dq * 4 + 3][r] = kv.w;
            *(float4*)&Vs[r][dq * 4] = *(const float4*)(vb + r * DH + dq * 4);
        }
        __syncthreads();

        float s[4][4] = {{0.f}};
        #pragma unroll
        for (int dg = 0; dg < 64; dg += 4) {
            float4 a4[4];
            #pragma unroll
            for (int i = 0; i < 4; ++i)
                a4[i] = *(const float4*)&Qs[ty * 4 + i][dg];
            #pragma unroll
            for (int t = 0; t < 4; ++t) {
                float4 b4 = *(const float4*)&Kt[dg + t][tx * 4];
                #pragma unroll
                for (int i = 0; i < 4; ++i) {
                    float avs = (t == 0) ? a4[i].x : (t == 1) ? a4[i].y
                              : (t == 2) ? a4[i].z : a4[i].w;
                    s[i][0] = fmaf(avs, b4.x, s[i][0]);
                    s[i][1] = fmaf(avs, b4.y, s[i][1]);
                    s[i][2] = fmaf(avs, b4.z, s[i][2]);
                    s[i][3] = fmaf(avs, b4.w, s[i][3]);
                }
            }
        }

        int kj[4];
        #pragma unroll
        for (int j = 0; j < 4; ++j)
            kj[j] = keep[(size_t)bh * SEQ + jt * 64 + tx * 4 + j];

        #pragma unroll
        for (int i = 0; i < 4; ++i) {
            #pragma unroll
            for (int j = 0; j < 4; ++j) {
                float p = (rowkeep[i] && kj[j]) ? __expf(s[i][j] * SCALE_F) : 0.f;
                lsum[i] += p;
                Ps[ty * 4 + i][tx * 4 + j] = p;
            }
        }
        __syncthreads();

        #pragma unroll 8
        for (int jj = 0; jj < 64; ++jj) {
            float4 vv = *(const float4*)&Vs[jj][tx * 4];
            float pr[4];
            #pragma unroll
            for (int i = 0; i < 4; ++i) pr[i] = Ps[ty * 4 + i][jj];
            #pragma unroll
            for (int i = 0; i < 4; ++i) {
                acc[i][0] = fmaf(pr[i], vv.x, acc[i][0]);
                acc[i][1] = fmaf(pr[i], vv.y, acc[i][1]);
                acc[i][2] = fmaf(pr[i], vv.z, acc[i][2]);
                acc[i][3] = fmaf(pr[i], vv.w, acc[i][3]);
            }
        }
    }

    #pragma unroll
    for (int i = 0; i < 4; ++i) {
        #pragma unroll
        for (int off = 8; off; off >>= 1)
            lsum[i] += __shfl_xor(lsum[i], off, 16);
    }

    #pragma unroll
    for (int i = 0; i < 4; ++i) {
        int tok = rt * 64 + ty * 4 + i;
        float inv = rowkeep[i] ? 1.0f / lsum[i] : 0.0f;
        float4 o;
        o.x = acc[i][0] * inv; o.y = acc[i][1] * inv;
        o.z = acc[i][2] * inv; o.w = acc[i][3] * inv;
        *(float4*)&att[((size_t)(b * SEQ + tok)) * DMODEL + h * DH + tx * 4] = o;
    }
}

// ---------------------------------------------------------------------------
extern "C" void kernel_launch(void* const* d_in, const int* in_sizes, int n_in,
                              void* d_out, int out_size, void* d_ws, size_t ws_size,
                              hipStream_t stream)
{
    const float* x     = (const float*)d_in[0];
    const float* w_qkv = (const float*)d_in[1];
    const float* w_out = (const float*)d_in[2];
    const float* b_out = (const float*)d_in[3];
    float* out = (float*)d_out;

    char* ws = (char*)d_ws;
    const size_t S = (size_t)NB * NH * SEQ * DH * sizeof(float);   // 16.78 MB

    // workspace slots (fits in the proven 4*S + 0.32MB footprint; d_out doubles
    // as scratch for x's hi/lo, dead before the final GEMM writes out)
    float* q   = (float*)(ws);                 // S1
    float* k   = (float*)(ws + S);             // S2
    float* v   = (float*)(ws + 2 * S);         // S3
    char*  S0  = ws + 3 * S;
    float* diag = (float*)(ws + 4 * S);
    unsigned char* keep = (unsigned char*)(ws + 4 * S + (size_t)NB * NH * SEQ * sizeof(float));

    u16* xh  = (u16*)d_out;                    // 8 MB
    u16* xl  = xh + (size_t)NB * SEQ * DMODEL; // 8 MB (16 <= 16.78 MB of d_out)
    u16* wqh = (u16*)S0;                       // 6 MB
    u16* wql = wqh + (size_t)3 * DMODEL * DMODEL;
    float* att = (float*)S0;                   // after wq dead (post-QKV GEMM)
    u16* atth = (u16*)(ws + S);                // S2, after k dead
    u16* attl = (u16*)(ws + 2 * S);            // S3, after v dead
    u16* woh  = (u16*)(ws);                    // S1, after q dead
    u16* wol  = woh + (size_t)DMODEL * DMODEL;

    // 1) decompose x and w_qkv
    decompose_hilo<<<2048, 256, 0, stream>>>(x, xh, xl, NB * SEQ * DMODEL / 8);
    decompose_hilo<<<1536, 256, 0, stream>>>(w_qkv, wqh, wql, 3 * DMODEL * DMODEL / 8);

    // 2) QKV projection (split-bf16 MFMA), scatter to [b*NH+h][tok][DH] fp32
    gemm_split<0><<<768, 256, 0, stream>>>(xh, xl, wqh, wql, nullptr, q, k, v);

    // 3) softmax diagonal (fp32)
    dim3 gAtt(NB * NH, SEQ / 64);
    attn_pass1<<<gAtt, 256, 0, stream>>>(q, k, diag);

    // 4) z-score mask
    mask_stats<<<NB * NH, 256, 0, stream>>>(diag, keep);

    // 5) masked softmax + PV (fp32)
    attn_pass2<<<gAtt, 256, 0, stream>>>(q, k, v, keep, att);

    // 6) decompose att and w_out into now-dead slots
    decompose_hilo<<<2048, 256, 0, stream>>>(att, atth, attl, NB * SEQ * DMODEL / 8);
    decompose_hilo<<<512, 256, 0, stream>>>(w_out, woh, wol, DMODEL * DMODEL / 8);

    // 7) output projection + bias (split-bf16 MFMA)
    gemm_split<1><<<256, 256, 0, stream>>>(atth, attl, woh, wol, b_out, out, nullptr, nullptr);
}

// Round 3
// 238.264 us; speedup vs baseline: 3.7074x; 2.3434x over previous
//
#include <hip/hip_runtime.h>
#include <hip/hip_bf16.h>

#define NB 4
#define SEQ 1024
#define DMODEL 1024
#define NH 16
#define DH 64
#define SCALE_F 0.125f
#define ZTH 1.5f

typedef __bf16 bf16x8 __attribute__((ext_vector_type(8)));
typedef float f32x4 __attribute__((ext_vector_type(4)));
typedef unsigned short u16;
typedef unsigned int u32;

__device__ __forceinline__ u32 bf16_rne(float f) {
    u32 u = __float_as_uint(f);
    return (u + 0x7fffu + ((u >> 16) & 1u)) >> 16;
}
__device__ __forceinline__ u32 pk2(float a, float b) {   // low u16 = a
    return bf16_rne(a) | (bf16_rne(b) << 16);
}

// ---------------------------------------------------------------------------
// fp32 -> bf16 hi + lo
// ---------------------------------------------------------------------------
__global__ __launch_bounds__(256)
void decompose_hilo(const float* __restrict__ in, u16* __restrict__ hi,
                    u16* __restrict__ lo, int n8)
{
    int i = blockIdx.x * 256 + threadIdx.x;
    if (i >= n8) return;
    const float4* p = (const float4*)in + (size_t)i * 2;
    float4 v0 = p[0], v1 = p[1];
    float f[8] = {v0.x, v0.y, v0.z, v0.w, v1.x, v1.y, v1.z, v1.w};
    u32 h[8], l[8];
    #pragma unroll
    for (int j = 0; j < 8; ++j) {
        u32 u = __float_as_uint(f[j]);
        u32 rh = (u + 0x7fffu + ((u >> 16) & 1u)) & 0xffff0000u;
        h[j] = rh >> 16;
        float fl = f[j] - __uint_as_float(rh);
        l[j] = bf16_rne(fl);
    }
    uint4 ho, lw;
    ho.x = h[0] | (h[1] << 16); ho.y = h[2] | (h[3] << 16);
    ho.z = h[4] | (h[5] << 16); ho.w = h[6] | (h[7] << 16);
    lw.x = l[0] | (l[1] << 16); lw.y = l[2] | (l[3] << 16);
    lw.z = l[4] | (l[5] << 16); lw.w = l[6] | (l[7] << 16);
    ((uint4*)hi)[i] = ho;
    ((uint4*)lo)[i] = lw;
}

// fp32 -> bf16 (single)
__global__ __launch_bounds__(256)
void to_bf16(const float* __restrict__ in, u16* __restrict__ out, int n8)
{
    int i = blockIdx.x * 256 + threadIdx.x;
    if (i >= n8) return;
    const float4* p = (const float4*)in + (size_t)i * 2;
    float4 v0 = p[0], v1 = p[1];
    uint4 o;
    o.x = pk2(v0.x, v0.y); o.y = pk2(v0.z, v0.w);
    o.z = pk2(v1.x, v1.y); o.w = pk2(v1.z, v1.w);
    ((uint4*)out)[i] = o;
}

// ---------------------------------------------------------------------------
// MFMA GEMM, C = A * B^T, A/B K-contiguous bf16 (hi/lo for MODE 0).
// MODE 0: QKV, 3-term split; epilogue -> qh/ql, kh/kl [bh][tok][64], vT [bh][d][tok]
// MODE 1: out-proj, 1-term; epilogue -> fp32 row-major + bias
// 128x128 tile, BK=32, 4 waves.
// ---------------------------------------------------------------------------
template<int MODE>
__global__ __launch_bounds__(256, 2)
void gemm_split(const u16* __restrict__ Ah, const u16* __restrict__ Al,
                const u16* __restrict__ Bh, const u16* __restrict__ Bl,
                const float* __restrict__ bias,
                u16* __restrict__ Qh, u16* __restrict__ Ql,
                u16* __restrict__ Kh, u16* __restrict__ Kl,
                u16* __restrict__ Vt, float* __restrict__ Cout)
{
    constexpr int M = NB * SEQ;
    constexpr int NCOL = (MODE == 0) ? 3 * DMODEL : DMODEL;
    constexpr int K = DMODEL;
    constexpr int NTN = NCOL / 128;
    constexpr int NWG = (M / 128) * NTN;
    constexpr int NT = (MODE == 0) ? 4 : 2;

    __shared__ u16 lds[NT][4][128][8];

    const int tid = threadIdx.x;
    const int bid = blockIdx.x;
    const int swz = (bid & 7) * (NWG >> 3) + (bid >> 3);
    const int mBase = (swz / NTN) * 128;
    const int nBase = (swz % NTN) * 128;

    const int wave = tid >> 6, lane = tid & 63;
    const int wr = wave >> 1, wc = wave & 1;
    const int rsel = lane & 15, ks = lane >> 4;

    const int r0 = tid >> 2, c0 = tid & 3;
    const size_t aoff0 = (size_t)(mBase + r0) * K + c0 * 8;
    const size_t aoff1 = (size_t)(mBase + 64 + r0) * K + c0 * 8;
    const size_t boff0 = (size_t)(nBase + r0) * K + c0 * 8;
    const size_t boff1 = (size_t)(nBase + 64 + r0) * K + c0 * 8;
    const int wrow0 = r0 ^ c0, wrow1 = (r0 ^ c0) + 64;

    const bf16x8 *rAh[4], *rAl[4], *rBh[4], *rBl[4];
    #pragma unroll
    for (int m = 0; m < 4; ++m) {
        int ar = (wr * 64 + m * 16 + rsel) ^ ks;
        rAh[m] = (const bf16x8*)&lds[0][ks][ar][0];
        if constexpr (MODE == 0) rAl[m] = (const bf16x8*)&lds[2][ks][ar][0];
    }
    #pragma unroll
    for (int n = 0; n < 4; ++n) {
        int bc = (wc * 64 + n * 16 + rsel) ^ ks;
        rBh[n] = (const bf16x8*)&lds[1][ks][bc][0];
        if constexpr (MODE == 0) rBl[n] = (const bf16x8*)&lds[3][ks][bc][0];
    }

    f32x4 acc[4][4];
    #pragma unroll
    for (int m = 0; m < 4; ++m)
        #pragma unroll
        for (int n = 0; n < 4; ++n)
            acc[m][n] = (f32x4)0.0f;

    uint4 sAh0, sAh1, sAl0, sAl1, sBh0, sBh1, sBl0, sBl1;
    #define LOADS(k0)                                                       \
        sAh0 = *(const uint4*)(Ah + aoff0 + (k0));                          \
        sAh1 = *(const uint4*)(Ah + aoff1 + (k0));                          \
        sBh0 = *(const uint4*)(Bh + boff0 + (k0));                          \
        sBh1 = *(const uint4*)(Bh + boff1 + (k0));                          \
        if constexpr (MODE == 0) {                                          \
            sAl0 = *(const uint4*)(Al + aoff0 + (k0));                      \
            sAl1 = *(const uint4*)(Al + aoff1 + (k0));                      \
            sBl0 = *(const uint4*)(Bl + boff0 + (k0));                      \
            sBl1 = *(const uint4*)(Bl + boff1 + (k0));                      \
        }

    LOADS(0)

    for (int it = 0; it < K / 32; ++it) {
        __syncthreads();
        *(uint4*)&lds[0][c0][wrow0][0] = sAh0;
        *(uint4*)&lds[0][c0][wrow1][0] = sAh1;
        *(uint4*)&lds[1][c0][wrow0][0] = sBh0;
        *(uint4*)&lds[1][c0][wrow1][0] = sBh1;
        if constexpr (MODE == 0) {
            *(uint4*)&lds[2][c0][wrow0][0] = sAl0;
            *(uint4*)&lds[2][c0][wrow1][0] = sAl1;
            *(uint4*)&lds[3][c0][wrow0][0] = sBl0;
            *(uint4*)&lds[3][c0][wrow1][0] = sBl1;
        }
        __syncthreads();
        if (it < K / 32 - 1) {
            int k0 = (it + 1) * 32;
            LOADS(k0)
        }
        bf16x8 ah[4], bh[4], al[4], bl[4];
        #pragma unroll
        for (int m = 0; m < 4; ++m) { ah[m] = *rAh[m]; if constexpr (MODE == 0) al[m] = *rAl[m]; }
        #pragma unroll
        for (int n = 0; n < 4; ++n) { bh[n] = *rBh[n]; if constexpr (MODE == 0) bl[n] = *rBl[n]; }
        #pragma unroll
        for (int m = 0; m < 4; ++m)
            #pragma unroll
            for (int n = 0; n < 4; ++n) {
                acc[m][n] = __builtin_amdgcn_mfma_f32_16x16x32_bf16(ah[m], bh[n], acc[m][n], 0, 0, 0);
                if constexpr (MODE == 0) {
                    acc[m][n] = __builtin_amdgcn_mfma_f32_16x16x32_bf16(ah[m], bl[n], acc[m][n], 0, 0, 0);
                    acc[m][n] = __builtin_amdgcn_mfma_f32_16x16x32_bf16(al[m], bh[n], acc[m][n], 0, 0, 0);
                }
            }
    }
    #undef LOADS

    const int rowq = lane >> 4;
    #pragma unroll
    for (int m = 0; m < 4; ++m) {
        #pragma unroll
        for (int n = 0; n < 4; ++n) {
            int grow0 = mBase + wr * 64 + m * 16 + rowq * 4;
            int gcol  = nBase + wc * 64 + n * 16 + rsel;
            if constexpr (MODE == 0) {
                int which = gcol >> 10, h = (gcol >> 6) & 15, d = gcol & 63;
                if (which == 2) {
                    // V transposed: [bh][d][tok], 4 consecutive tok -> 8B store
                    int b = grow0 >> 10, tok0 = grow0 & 1023;
                    ushort4 vv;
                    vv.x = (u16)bf16_rne(acc[m][n][0]);
                    vv.y = (u16)bf16_rne(acc[m][n][1]);
                    vv.z = (u16)bf16_rne(acc[m][n][2]);
                    vv.w = (u16)bf16_rne(acc[m][n][3]);
                    *(ushort4*)&Vt[((size_t)(b * NH + h) * DH + d) * SEQ + tok0] = vv;
                } else {
                    u16* Ph = (which == 0) ? Qh : Kh;
                    u16* Pl = (which == 0) ? Ql : Kl;
                    #pragma unroll
                    for (int r = 0; r < 4; ++r) {
                        int grow = grow0 + r;
                        int b = grow >> 10, tok = grow & 1023;
                        size_t idx = ((size_t)(b * NH + h) * SEQ + tok) * DH + d;
                        float f = acc[m][n][r];
                        u32 u = __float_as_uint(f);
                        u32 rh = (u + 0x7fffu + ((u >> 16) & 1u)) & 0xffff0000u;
                        Ph[idx] = (u16)(rh >> 16);
                        Pl[idx] = (u16)bf16_rne(f - __uint_as_float(rh));
                    }
                }
            } else {
                float bb = bias[gcol];
                #pragma unroll
                for (int r = 0; r < 4; ++r)
                    Cout[(size_t)(grow0 + r) * NCOL + gcol] = acc[m][n][r] + bb;
            }
        }
    }
}

// ---------------------------------------------------------------------------
// Pass 1 (MFMA, swapped operands, 4-term split): diag of softmax(dots).
// Block: 4 waves x 32 q-rows = 128-q stripe; wave-private, no barriers.
// D = mfma(K_tile, Q): lane col = q (lane&15), rows = 4 k's per quad.
// ---------------------------------------------------------------------------
__global__ __launch_bounds__(256)
void attn_pass1_mfma(const u16* __restrict__ qhp, const u16* __restrict__ qlp,
                     const u16* __restrict__ khp, const u16* __restrict__ klp,
                     float* __restrict__ diag)
{
    const int bh = blockIdx.x;
    const int tid = threadIdx.x;
    const int wid = tid >> 6, lane = tid & 63;
    const int qloc = lane & 15, quad = lane >> 4;
    const int qbase = blockIdx.y * 128 + wid * 32;
    const size_t base = (size_t)bh * SEQ;

    bf16x8 qbh[2][2], qbl[2][2];
    #pragma unroll
    for (int qf = 0; qf < 2; ++qf)
        #pragma unroll
        for (int dc = 0; dc < 2; ++dc) {
            size_t off = (base + qbase + qf * 16 + qloc) * DH + dc * 32 + quad * 8;
            qbh[qf][dc] = *(const bf16x8*)(qhp + off);
            qbl[qf][dc] = *(const bf16x8*)(qlp + off);
        }

    float lsum[2] = {0.f, 0.f}, sd[2] = {0.f, 0.f};

    for (int cb = 0; cb < SEQ; cb += 32) {
        bf16x8 ah[2][2], al[2][2];
        #pragma unroll
        for (int t = 0; t < 2; ++t)
            #pragma unroll
            for (int dc = 0; dc < 2; ++dc) {
                size_t off = (base + cb + t * 16 + qloc) * DH + dc * 32 + quad * 8;
                ah[t][dc] = *(const bf16x8*)(khp + off);
                al[t][dc] = *(const bf16x8*)(klp + off);
            }
        const bool dchunk = (cb == qbase);   // qbase is 32-aligned
        #pragma unroll
        for (int qf = 0; qf < 2; ++qf)
            #pragma unroll
            for (int t = 0; t < 2; ++t) {
                f32x4 d = (f32x4)0.f;
                #pragma unroll
                for (int dc = 0; dc < 2; ++dc) {
                    d = __builtin_amdgcn_mfma_f32_16x16x32_bf16(ah[t][dc], qbh[qf][dc], d, 0, 0, 0);
                    d = __builtin_amdgcn_mfma_f32_16x16x32_bf16(ah[t][dc], qbl[qf][dc], d, 0, 0, 0);
                    d = __builtin_amdgcn_mfma_f32_16x16x32_bf16(al[t][dc], qbh[qf][dc], d, 0, 0, 0);
                    d = __builtin_amdgcn_mfma_f32_16x16x32_bf16(al[t][dc], qbl[qf][dc], d, 0, 0, 0);
                }
                #pragma unroll
                for (int r = 0; r < 4; ++r) {
                    float ex = __expf(d[r] * SCALE_F);
                    lsum[qf] += ex;
                    if (dchunk && t == qf && quad == (qloc >> 2) && r == (qloc & 3))
                        sd[qf] = ex;
                }
            }
    }
    #pragma unroll
    for (int qf = 0; qf < 2; ++qf) {
        lsum[qf] += __shfl_xor(lsum[qf], 16);
        lsum[qf] += __shfl_xor(lsum[qf], 32);
        sd[qf]   += __shfl_xor(sd[qf], 16);
        sd[qf]   += __shfl_xor(sd[qf], 32);
    }
    if (quad == 0) {
        diag[base + qbase + qloc]      = sd[0] / lsum[0];
        diag[base + qbase + 16 + qloc] = sd[1] / lsum[1];
    }
}

// ---------------------------------------------------------------------------
// Per-(b,h) z-score mask (unchanged).
// ---------------------------------------------------------------------------
__global__ __launch_bounds__(256)
void mask_stats(const float* __restrict__ diag, unsigned char* __restrict__ keep)
{
    __shared__ float red[256];
    const int bh = blockIdx.x, tid = threadIdx.x;
    const float* d = diag + (size_t)bh * SEQ;
    float4 v = *(const float4*)(d + tid * 4);
    red[tid] = (v.x + v.y) + (v.z + v.w);
    __syncthreads();
    for (int w = 128; w > 0; w >>= 1) {
        if (tid < w) red[tid] += red[tid + w];
        __syncthreads();
    }
    float mu = red[0] * (1.0f / 1024.0f);
    __syncthreads();
    float dx0 = v.x - mu, dx1 = v.y - mu, dx2 = v.z - mu, dx3 = v.w - mu;
    red[tid] = (dx0 * dx0 + dx1 * dx1) + (dx2 * dx2 + dx3 * dx3);
    __syncthreads();
    for (int w = 128; w > 0; w >>= 1) {
        if (tid < w) red[tid] += red[tid + w];
        __syncthreads();
    }
    float sd = sqrtf(red[0] * (1.0f / 1023.0f));
    uchar4 kv;
    kv.x = (fabsf(dx0 / sd) <= ZTH) ? 1 : 0;
    kv.y = (fabsf(dx1 / sd) <= ZTH) ? 1 : 0;
    kv.z = (fabsf(dx2 / sd) <= ZTH) ? 1 : 0;
    kv.w = (fabsf(dx3 / sd) <= ZTH) ? 1 : 0;
    *(uchar4*)&keep[(size_t)bh * SEQ + tid * 4] = kv;
}

// ---------------------------------------------------------------------------
// Pass 2 (MFMA): masked softmax + PV.  Swapped QK^T (single bf16 term),
// P packed bf16 into wave-private LDS [32 q][32 k] (granule-XOR swizzle),
// PV = mfma(VT_frag, P_frag) accumulating OUT^T.  att out: bf16 [b][tok][1024].
// No barriers (wave-private LDS).
// ---------------------------------------------------------------------------
__global__ __launch_bounds__(256)
void attn_pass2_mfma(const u16* __restrict__ qhp, const u16* __restrict__ khp,
                     const u16* __restrict__ vTp, const unsigned char* __restrict__ keep,
                     u16* __restrict__ att)
{
    __shared__ u16 P[4][32][32];   // 8 KB
    const int bh = blockIdx.x;
    const int b = bh >> 4, h = bh & 15;
    const int tid = threadIdx.x;
    const int wid = tid >> 6, lane = tid & 63;
    const int qloc = lane & 15, quad = lane >> 4;
    const int qbase = blockIdx.y * 128 + wid * 32;
    const size_t base = (size_t)bh * SEQ;

    bf16x8 qb[2][2];
    #pragma unroll
    for (int qf = 0; qf < 2; ++qf)
        #pragma unroll
        for (int dc = 0; dc < 2; ++dc)
            qb[qf][dc] = *(const bf16x8*)(qhp + (base + qbase + qf * 16 + qloc) * DH + dc * 32 + quad * 8);

    const bool rk[2] = {keep[base + qbase + qloc] != 0,
                        keep[base + qbase + 16 + qloc] != 0};

    // LDS byte offsets (within this wave's [32][32] u16 = 2048B region)
    char* Pw = (char*)&P[wid][0][0];
    int woff[2][2], roff[2];
    #pragma unroll
    for (int qf = 0; qf < 2; ++qf) {
        int row = qf * 16 + qloc;
        #pragma unroll
        for (int t = 0; t < 2; ++t) {
            int gran = 2 * t + (quad >> 1);
            woff[qf][t] = row * 64 + ((gran ^ (qloc & 3)) << 4) + (quad & 1) * 8;
        }
        roff[qf] = row * 64 + ((quad ^ (qloc & 3)) << 4);
    }

    f32x4 acc2[2][4];
    #pragma unroll
    for (int qf = 0; qf < 2; ++qf)
        #pragma unroll
        for (int dt = 0; dt < 4; ++dt)
            acc2[qf][dt] = (f32x4)0.f;
    float lsum[2] = {0.f, 0.f};

    for (int cb = 0; cb < SEQ; cb += 32) {
        bf16x8 ah[2][2];
        #pragma unroll
        for (int t = 0; t < 2; ++t)
            #pragma unroll
            for (int dc = 0; dc < 2; ++dc)
                ah[t][dc] = *(const bf16x8*)(khp + (base + cb + t * 16 + qloc) * DH + dc * 32 + quad * 8);
        bf16x8 va[4];
        #pragma unroll
        for (int dt = 0; dt < 4; ++dt)
            va[dt] = *(const bf16x8*)(vTp + ((size_t)bh * DH + dt * 16 + qloc) * SEQ + cb + quad * 8);
        u32 ku[2];
        #pragma unroll
        for (int t = 0; t < 2; ++t)
            ku[t] = *(const u32*)(keep + base + cb + t * 16 + quad * 4);

        #pragma unroll
        for (int qf = 0; qf < 2; ++qf)
            #pragma unroll
            for (int t = 0; t < 2; ++t) {
                f32x4 d = (f32x4)0.f;
                d = __builtin_amdgcn_mfma_f32_16x16x32_bf16(ah[t][0], qb[qf][0], d, 0, 0, 0);
                d = __builtin_amdgcn_mfma_f32_16x16x32_bf16(ah[t][1], qb[qf][1], d, 0, 0, 0);
                float p[4];
                #pragma unroll
                for (int r = 0; r < 4; ++r) {
                    float e = __expf(d[r] * SCALE_F);
                    bool kk = ((ku[t] >> (r * 8)) & 0xffu) != 0;
                    p[r] = (rk[qf] && kk) ? e : 0.f;
                    lsum[qf] += p[r];
                }
                uint2 w;
                w.x = pk2(p[0], p[1]);
                w.y = pk2(p[2], p[3]);
                *(uint2*)(Pw + woff[qf][t]) = w;
            }

        bf16x8 pb[2];
        #pragma unroll
        for (int qf = 0; qf < 2; ++qf)
            pb[qf] = *(const bf16x8*)(Pw + roff[qf]);
        #pragma unroll
        for (int qf = 0; qf < 2; ++qf)
            #pragma unroll
            for (int dt = 0; dt < 4; ++dt)
                acc2[qf][dt] = __builtin_amdgcn_mfma_f32_16x16x32_bf16(va[dt], pb[qf], acc2[qf][dt], 0, 0, 0);
    }

    #pragma unroll
    for (int qf = 0; qf < 2; ++qf) {
        lsum[qf] += __shfl_xor(lsum[qf], 16);
        lsum[qf] += __shfl_xor(lsum[qf], 32);
        float inv = rk[qf] ? 1.0f / lsum[qf] : 0.0f;
        int tok = qbase + qf * 16 + qloc;
        #pragma unroll
        for (int dt = 0; dt < 4; ++dt) {
            uint2 w;
            w.x = pk2(acc2[qf][dt][0] * inv, acc2[qf][dt][1] * inv);
            w.y = pk2(acc2[qf][dt][2] * inv, acc2[qf][dt][3] * inv);
            *(uint2*)&att[((size_t)(b * SEQ + tok)) * DMODEL + h * DH + dt * 16 + quad * 4] = w;
        }
    }
}

// ---------------------------------------------------------------------------
extern "C" void kernel_launch(void* const* d_in, const int* in_sizes, int n_in,
                              void* d_out, int out_size, void* d_ws, size_t ws_size,
                              hipStream_t stream)
{
    const float* x     = (const float*)d_in[0];
    const float* w_qkv = (const float*)d_in[1];
    const float* w_out = (const float*)d_in[2];
    const float* b_out = (const float*)d_in[3];
    float* out = (float*)d_out;

    char* ws = (char*)d_ws;
    const size_t T = (size_t)NB * NH * SEQ * DH * sizeof(u16);   // 8 MB per head-tensor

    u16* qh   = (u16*)(ws);
    u16* ql   = (u16*)(ws + T);
    u16* kh   = (u16*)(ws + 2 * T);
    u16* kl   = (u16*)(ws + 3 * T);
    u16* vT   = (u16*)(ws + 4 * T);
    u16* attb = (u16*)(ws + 5 * T);
    u16* wob  = (u16*)(ws + 6 * T);                               // 2 MB
    float* diag = (float*)(ws + 6 * T + (size_t)DMODEL * DMODEL * sizeof(u16));
    unsigned char* keep = (unsigned char*)((char*)diag + (size_t)NB * NH * SEQ * sizeof(float));
    u16* wqh  = (u16*)((char*)keep + (size_t)NB * NH * SEQ);
    u16* wql  = wqh + (size_t)3 * DMODEL * DMODEL;

    u16* xh = (u16*)d_out;                                        // d_out as scratch
    u16* xl = xh + (size_t)NB * SEQ * DMODEL;                     // 16 MB total

    // 1) decompose inputs
    decompose_hilo<<<2048, 256, 0, stream>>>(x, xh, xl, NB * SEQ * DMODEL / 8);
    decompose_hilo<<<1536, 256, 0, stream>>>(w_qkv, wqh, wql, 3 * DMODEL * DMODEL / 8);
    to_bf16<<<512, 256, 0, stream>>>(w_out, wob, DMODEL * DMODEL / 8);

    // 2) QKV projection -> qh/ql, kh/kl, vT
    gemm_split<0><<<768, 256, 0, stream>>>(xh, xl, wqh, wql, nullptr,
                                           qh, ql, kh, kl, vT, nullptr);

    // 3) softmax diagonal (4-term split MFMA)
    dim3 gA(NB * NH, SEQ / 128);
    attn_pass1_mfma<<<gA, 256, 0, stream>>>(qh, ql, kh, kl, diag);

    // 4) z-score mask
    mask_stats<<<NB * NH, 256, 0, stream>>>(diag, keep);

    // 5) masked softmax + PV -> att bf16 [b][tok][1024]
    attn_pass2_mfma<<<gA, 256, 0, stream>>>(qh, kh, vT, keep, attb);

    // 6) output projection + bias
    gemm_split<1><<<256, 256, 0, stream>>>(attb, nullptr, wob, nullptr, b_out,
                                           nullptr, nullptr, nullptr, nullptr, nullptr, out);
}